// Round 1
// baseline (933.533 us; speedup 1.0000x reference)
//
#include <hip/hip_runtime.h>
#include <hip/hip_bf16.h>

// ---------------------------------------------------------------------------
// GCN forward:  3 x [GCNConv + ReLU]  ->  mean-pool per graph  ->  FFN
// Factorization: out[i] = relu( dis[i] * ( y[i] + sum_{e:col=i} y[row_e] ) + b )
//                with y = rowscale(dis) * (h @ W),  dis[i] = rsqrt(deg[i]+1)
// CSR (grouped by destination col) built on-device each launch -> no atomics
// in the per-channel aggregation hot path.
// ---------------------------------------------------------------------------

#define THREADS 256

// ---------------- small setup kernels ----------------

__global__ void degree_kernel(const int* __restrict__ col, int* __restrict__ deg, int E) {
    int e = blockIdx.x * THREADS + threadIdx.x;
    if (e < E) atomicAdd(&deg[col[e]], 1);
}

__global__ void dis_kernel(const int* __restrict__ deg, float* __restrict__ dis, int N) {
    int i = blockIdx.x * THREADS + threadIdx.x;
    if (i < N) dis[i] = rsqrtf((float)(deg[i] + 1));   // +1 self-loop; deg>=1 always
}

// single-block exclusive scan, 4 elements/thread/iter. out has n+1 slots.
__global__ void exscan_kernel(const int* __restrict__ in, int* __restrict__ out, int n) {
    __shared__ int wsum[4];
    __shared__ int carry_s;
    if (threadIdx.x == 0) carry_s = 0;
    __syncthreads();
    int lane = threadIdx.x & 63, wid = threadIdx.x >> 6;
    for (int base = 0; base < n; base += THREADS * 4) {
        int i0 = base + threadIdx.x * 4;
        int v0 = 0, v1 = 0, v2 = 0, v3 = 0;
        if (i0 + 3 < n) {
            int4 v = *(const int4*)&in[i0];
            v0 = v.x; v1 = v.y; v2 = v.z; v3 = v.w;
        } else {
            if (i0 + 0 < n) v0 = in[i0 + 0];
            if (i0 + 1 < n) v1 = in[i0 + 1];
            if (i0 + 2 < n) v2 = in[i0 + 2];
            if (i0 + 3 < n) v3 = in[i0 + 3];
        }
        int s = v0 + v1 + v2 + v3;
        int inc = s;
        #pragma unroll
        for (int d = 1; d < 64; d <<= 1) {
            int t = __shfl_up(inc, d);
            if (lane >= d) inc += t;
        }
        if (lane == 63) wsum[wid] = inc;
        __syncthreads();
        int add = carry_s;
        for (int w = 0; w < wid; ++w) add += wsum[w];
        int ex = add + inc - s;   // exclusive prefix of this thread's 4-chunk
        if (i0 + 0 < n) out[i0 + 0] = ex;
        if (i0 + 1 < n) out[i0 + 1] = ex + v0;
        if (i0 + 2 < n) out[i0 + 2] = ex + v0 + v1;
        if (i0 + 3 < n) out[i0 + 3] = ex + v0 + v1 + v2;
        __syncthreads();
        if (threadIdx.x == 0) carry_s += wsum[0] + wsum[1] + wsum[2] + wsum[3];
        __syncthreads();
    }
    if (threadIdx.x == 0) out[n] = carry_s;
}

__global__ void csr_fill_kernel(const int* __restrict__ row, const int* __restrict__ col,
                                const int* __restrict__ offs, int* __restrict__ fill,
                                int* __restrict__ srcs, int E) {
    int e = blockIdx.x * THREADS + threadIdx.x;
    if (e < E) {
        int c = col[e];
        int pos = offs[c] + atomicAdd(&fill[c], 1);
        srcs[pos] = row[e];
    }
}

__global__ void gcount_kernel(const int* __restrict__ batch, int* __restrict__ gcnt, int N) {
    int i = blockIdx.x * THREADS + threadIdx.x;
    if (i < N) atomicAdd(&gcnt[batch[i]], 1);
}

// ---------------- GEMM: Y[m,n] = dis[m] * sum_k A[m,k] W[k,n] ----------------
// 64x64 tile, BK=16, 256 threads, 4x4 micro-tile per thread. fp32 vector ALU.

#define BM 64
#define BN 64
#define BK 16

__global__ __launch_bounds__(256) void gemm_scale_kernel(
    const float* __restrict__ A, const float* __restrict__ W,
    const float* __restrict__ dis, float* __restrict__ Y,
    int M, int K, int N) {
    __shared__ float As[BK][BM + 4];   // padded: conflict-light, keeps float4 align
    __shared__ float Bs[BK][BN + 4];
    int tid = threadIdx.x;
    int m0 = blockIdx.y * BM;
    int n0 = blockIdx.x * BN;
    int tx = tid & 15, ty = tid >> 4;

    float acc[4][4] = {};

    for (int k0 = 0; k0 < K; k0 += BK) {
        // A tile (64 rows x 16 k): thread -> row tid/4, k-cols (tid%4)*4..+3
        {
            int r = tid >> 2;
            int c = (tid & 3) * 4;
            int gr = m0 + r;
            float4 v = make_float4(0.f, 0.f, 0.f, 0.f);
            if (gr < M) v = *(const float4*)&A[(size_t)gr * K + k0 + c];
            As[c + 0][r] = v.x;
            As[c + 1][r] = v.y;
            As[c + 2][r] = v.z;
            As[c + 3][r] = v.w;
        }
        // B tile (16 k x 64 n): thread -> k-row tid/16, n-cols (tid%16)*4
        {
            int br = tid >> 4;
            int bc = (tid & 15) * 4;
            *(float4*)&Bs[br][bc] = *(const float4*)&W[(size_t)(k0 + br) * N + n0 + bc];
        }
        __syncthreads();
        #pragma unroll
        for (int k = 0; k < BK; ++k) {
            float4 av = *(const float4*)&As[k][ty * 4];
            float4 bv = *(const float4*)&Bs[k][tx * 4];
            float a0 = av.x, a1 = av.y, a2 = av.z, a3 = av.w;
            float b0 = bv.x, b1 = bv.y, b2 = bv.z, b3 = bv.w;
            acc[0][0] = fmaf(a0, b0, acc[0][0]); acc[0][1] = fmaf(a0, b1, acc[0][1]);
            acc[0][2] = fmaf(a0, b2, acc[0][2]); acc[0][3] = fmaf(a0, b3, acc[0][3]);
            acc[1][0] = fmaf(a1, b0, acc[1][0]); acc[1][1] = fmaf(a1, b1, acc[1][1]);
            acc[1][2] = fmaf(a1, b2, acc[1][2]); acc[1][3] = fmaf(a1, b3, acc[1][3]);
            acc[2][0] = fmaf(a2, b0, acc[2][0]); acc[2][1] = fmaf(a2, b1, acc[2][1]);
            acc[2][2] = fmaf(a2, b2, acc[2][2]); acc[2][3] = fmaf(a2, b3, acc[2][3]);
            acc[3][0] = fmaf(a3, b0, acc[3][0]); acc[3][1] = fmaf(a3, b1, acc[3][1]);
            acc[3][2] = fmaf(a3, b2, acc[3][2]); acc[3][3] = fmaf(a3, b3, acc[3][3]);
        }
        __syncthreads();
    }

    #pragma unroll
    for (int i = 0; i < 4; ++i) {
        int gr = m0 + ty * 4 + i;
        if (gr < M) {
            float d = dis[gr];
            float4 o;
            o.x = acc[i][0] * d; o.y = acc[i][1] * d;
            o.z = acc[i][2] * d; o.w = acc[i][3] * d;
            *(float4*)&Y[(size_t)gr * N + n0 + tx * 4] = o;
        }
    }
}

// ---------------- aggregation: h[i] = relu(dis[i]*(y[i]+sum srcs) + b) -------
// one wave (64 lanes x float4 = 256 ch) per node, 4 nodes per block.

__global__ __launch_bounds__(256) void aggregate_kernel(
    const float* __restrict__ Y, const int* __restrict__ offs,
    const int* __restrict__ srcs, const float* __restrict__ dis,
    const float* __restrict__ bias, float* __restrict__ H, int N) {
    int node = blockIdx.x * 4 + (threadIdx.x >> 6);
    if (node >= N) return;
    int lane = threadIdx.x & 63;
    const float4* Yv = (const float4*)Y;
    float4 acc = Yv[(size_t)node * 64 + lane];   // self-loop term y[i]
    int s = offs[node], e = offs[node + 1];
    for (int i = s; i < e; ++i) {
        int src = srcs[i];
        float4 v = Yv[(size_t)src * 64 + lane];
        acc.x += v.x; acc.y += v.y; acc.z += v.z; acc.w += v.w;
    }
    float d = dis[node];
    float4 b = ((const float4*)bias)[lane];
    float4 r;
    r.x = fmaxf(fmaf(d, acc.x, b.x), 0.f);
    r.y = fmaxf(fmaf(d, acc.y, b.y), 0.f);
    r.z = fmaxf(fmaf(d, acc.z, b.z), 0.f);
    r.w = fmaxf(fmaf(d, acc.w, b.w), 0.f);
    ((float4*)H)[(size_t)node * 64 + lane] = r;
}

// ---------------- mean pool per graph (batch sorted -> contiguous ranges) ----

__global__ __launch_bounds__(256) void pool_kernel(
    const float* __restrict__ H, const int* __restrict__ goff,
    float* __restrict__ pooled) {
    int g = blockIdx.x;
    int t = threadIdx.x;
    int s = goff[g], e = goff[g + 1];
    float acc = 0.f;
    for (int n = s; n < e; ++n) acc += H[(size_t)n * 256 + t];
    float cnt = (float)(e - s);
    pooled[g * 256 + t] = acc / fmaxf(cnt, 1.f);
}

// ---------------- FFN: relu(pooled@Wf+bf) @ Wo + bo,  one block per graph ----

__global__ __launch_bounds__(256) void ffn_kernel(
    const float* __restrict__ pooled, const float* __restrict__ Wf,
    const float* __restrict__ bf, const float* __restrict__ Wo,
    const float* __restrict__ bo, float* __restrict__ out) {
    __shared__ float p[256];
    __shared__ float red[256];
    int g = blockIdx.x, t = threadIdx.x;
    p[t] = pooled[g * 256 + t];
    __syncthreads();
    float s = bf[t];
    for (int k = 0; k < 256; ++k) s = fmaf(p[k], Wf[k * 256 + t], s);
    float gv = fmaxf(s, 0.f);
    red[t] = gv * Wo[t];
    __syncthreads();
    for (int o = 128; o > 0; o >>= 1) {
        if (t < o) red[t] += red[t + o];
        __syncthreads();
    }
    if (t == 0) out[g] = red[0] + bo[0];
}

// ---------------------------------------------------------------------------

extern "C" void kernel_launch(void* const* d_in, const int* in_sizes, int n_in,
                              void* d_out, int out_size, void* d_ws, size_t ws_size,
                              hipStream_t stream) {
    const float* x   = (const float*)d_in[0];
    const int*   ei  = (const int*)d_in[1];
    const int*   bat = (const int*)d_in[2];
    const float* W1  = (const float*)d_in[3];
    const float* b1  = (const float*)d_in[4];
    const float* W2  = (const float*)d_in[5];
    const float* b2  = (const float*)d_in[6];
    const float* W3  = (const float*)d_in[7];
    const float* b3  = (const float*)d_in[8];
    const float* Wf  = (const float*)d_in[9];
    const float* bf  = (const float*)d_in[10];
    const float* Wo  = (const float*)d_in[11];
    const float* bo  = (const float*)d_in[12];
    float* out = (float*)d_out;

    const int N  = in_sizes[2];        // 50000 nodes
    const int E  = in_sizes[1] / 2;    // 800000 edges
    const int IC = in_sizes[0] / N;    // 128
    const int H  = 256;
    const int G  = out_size;           // 256 graphs
    const int* row = ei;
    const int* col = ei + E;

    char* w = (char*)d_ws;
    size_t off = 0;
    auto alloc = [&](size_t bytes) -> void* {
        void* p = w + off;
        off += (bytes + 255) & ~(size_t)255;
        return p;
    };
    int*   deg    = (int*)alloc((size_t)N * 4);
    float* dis    = (float*)alloc((size_t)N * 4);
    int*   offs   = (int*)alloc((size_t)(N + 1) * 4);
    int*   fill   = (int*)alloc((size_t)N * 4);
    int*   srcs   = (int*)alloc((size_t)E * 4);
    int*   gcnt   = (int*)alloc((size_t)G * 4);
    int*   goff   = (int*)alloc((size_t)(G + 1) * 4);
    float* bufA   = (float*)alloc((size_t)N * H * 4);
    float* bufB   = (float*)alloc((size_t)N * H * 4);
    float* pooled = (float*)alloc((size_t)G * H * 4);
    (void)ws_size; (void)n_in;

    hipMemsetAsync(deg,  0, (size_t)N * 4, stream);
    hipMemsetAsync(fill, 0, (size_t)N * 4, stream);
    hipMemsetAsync(gcnt, 0, (size_t)G * 4, stream);

    degree_kernel<<<(E + THREADS - 1) / THREADS, THREADS, 0, stream>>>(col, deg, E);
    dis_kernel<<<(N + THREADS - 1) / THREADS, THREADS, 0, stream>>>(deg, dis, N);
    exscan_kernel<<<1, THREADS, 0, stream>>>(deg, offs, N);
    csr_fill_kernel<<<(E + THREADS - 1) / THREADS, THREADS, 0, stream>>>(row, col, offs, fill, srcs, E);
    gcount_kernel<<<(N + THREADS - 1) / THREADS, THREADS, 0, stream>>>(bat, gcnt, N);
    exscan_kernel<<<1, THREADS, 0, stream>>>(gcnt, goff, G);

    dim3 gemm_grid(H / BN, (N + BM - 1) / BM);
    // layer 1: x[50000,128] -> bufA (y1) -> bufB (h1)
    gemm_scale_kernel<<<gemm_grid, 256, 0, stream>>>(x, W1, dis, bufA, N, IC, H);
    aggregate_kernel<<<(N + 3) / 4, 256, 0, stream>>>(bufA, offs, srcs, dis, b1, bufB, N);
    // layer 2
    gemm_scale_kernel<<<gemm_grid, 256, 0, stream>>>(bufB, W2, dis, bufA, N, H, H);
    aggregate_kernel<<<(N + 3) / 4, 256, 0, stream>>>(bufA, offs, srcs, dis, b2, bufB, N);
    // layer 3
    gemm_scale_kernel<<<gemm_grid, 256, 0, stream>>>(bufB, W3, dis, bufA, N, H, H);
    aggregate_kernel<<<(N + 3) / 4, 256, 0, stream>>>(bufA, offs, srcs, dis, b3, bufB, N);

    pool_kernel<<<G, 256, 0, stream>>>(bufB, goff, pooled);
    ffn_kernel<<<G, 256, 0, stream>>>(pooled, Wf, bf, Wo, bo, out);
}

// Round 2
// 764.930 us; speedup vs baseline: 1.2204x; 1.2204x over previous
//
#include <hip/hip_runtime.h>
#include <hip/hip_bf16.h>

// ---------------------------------------------------------------------------
// GCN forward, restructured:  per layer  h' = ReLU( (Â h) @ W + b )
//   (aggregation commutes with the linear map, so aggregate FIRST:
//    layer-1 gathers 128-ch rows instead of 256-ch -> half the traffic)
// Aggregate epilogue emits bf16 hi/lo split buffers; GEMM runs 3-pass
// bf16 MFMA (hi*hi + hi*lo + lo*hi) == fp32 accuracy (~2^-17 rel error).
// CSR built on-device each launch; no atomics in per-channel hot paths.
// ---------------------------------------------------------------------------

#define THREADS 256

typedef short bf16x8 __attribute__((ext_vector_type(8)));
typedef float f32x4  __attribute__((ext_vector_type(4)));

__device__ __forceinline__ unsigned bf16_rne_bits(float f) {
    unsigned x = __float_as_uint(f);
    return (x + 0x7fffu + ((x >> 16) & 1u)) >> 16;
}

// ---------------- small setup kernels ----------------

__global__ void degree_kernel(const int* __restrict__ col, int* __restrict__ deg, int E) {
    int e = blockIdx.x * THREADS + threadIdx.x;
    if (e < E) atomicAdd(&deg[col[e]], 1);
}

__global__ void dis_kernel(const int* __restrict__ deg, float* __restrict__ dis, int N) {
    int i = blockIdx.x * THREADS + threadIdx.x;
    if (i < N) dis[i] = rsqrtf((float)(deg[i] + 1));   // +1 self-loop
}

// single-block exclusive scan, 4 elements/thread/iter. out has n+1 slots.
__global__ void exscan_kernel(const int* __restrict__ in, int* __restrict__ out, int n) {
    __shared__ int wsum[4];
    __shared__ int carry_s;
    if (threadIdx.x == 0) carry_s = 0;
    __syncthreads();
    int lane = threadIdx.x & 63, wid = threadIdx.x >> 6;
    for (int base = 0; base < n; base += THREADS * 4) {
        int i0 = base + threadIdx.x * 4;
        int v0 = 0, v1 = 0, v2 = 0, v3 = 0;
        if (i0 + 3 < n) {
            int4 v = *(const int4*)&in[i0];
            v0 = v.x; v1 = v.y; v2 = v.z; v3 = v.w;
        } else {
            if (i0 + 0 < n) v0 = in[i0 + 0];
            if (i0 + 1 < n) v1 = in[i0 + 1];
            if (i0 + 2 < n) v2 = in[i0 + 2];
            if (i0 + 3 < n) v3 = in[i0 + 3];
        }
        int s = v0 + v1 + v2 + v3;
        int inc = s;
        #pragma unroll
        for (int d = 1; d < 64; d <<= 1) {
            int t = __shfl_up(inc, d);
            if (lane >= d) inc += t;
        }
        if (lane == 63) wsum[wid] = inc;
        __syncthreads();
        int add = carry_s;
        for (int w = 0; w < wid; ++w) add += wsum[w];
        int ex = add + inc - s;
        if (i0 + 0 < n) out[i0 + 0] = ex;
        if (i0 + 1 < n) out[i0 + 1] = ex + v0;
        if (i0 + 2 < n) out[i0 + 2] = ex + v0 + v1;
        if (i0 + 3 < n) out[i0 + 3] = ex + v0 + v1 + v2;
        __syncthreads();
        if (threadIdx.x == 0) carry_s += wsum[0] + wsum[1] + wsum[2] + wsum[3];
        __syncthreads();
    }
    if (threadIdx.x == 0) out[n] = carry_s;
}

// uses deg as the countdown (deg no longer needed after dis_kernel)
__global__ void csr_fill_kernel(const int* __restrict__ row, const int* __restrict__ col,
                                const int* __restrict__ offs, int* __restrict__ deg,
                                int* __restrict__ srcs, int E) {
    int e = blockIdx.x * THREADS + threadIdx.x;
    if (e < E) {
        int c = col[e];
        int old = atomicSub(&deg[c], 1);
        srcs[offs[c] + old - 1] = row[e];
    }
}

__global__ void gcount_kernel(const int* __restrict__ batch, int* __restrict__ gcnt, int N) {
    int i = blockIdx.x * THREADS + threadIdx.x;
    if (i < N) atomicAdd(&gcnt[batch[i]], 1);
}

// W[K,N] fp32 -> transposed bf16 hi/lo  Thi/Tlo[N][K]
__global__ void wsplit_kernel(const float* __restrict__ W, unsigned short* __restrict__ Thi,
                              unsigned short* __restrict__ Tlo, int K, int Nc) {
    int i = blockIdx.x * THREADS + threadIdx.x;
    if (i >= K * Nc) return;
    int k = i / Nc, n = i % Nc;
    float w = W[i];
    unsigned hb = bf16_rne_bits(w);
    float hf = __uint_as_float(hb << 16);
    unsigned lb = bf16_rne_bits(w - hf);
    Thi[n * K + k] = (unsigned short)hb;
    Tlo[n * K + k] = (unsigned short)lb;
}

// ---------------- aggregation: a[i] = dis[i]*(dis[i]*x[i] + sum dis[s]*x[s]) --
// emits bf16 hi/lo split of the result (A operand of the following GEMM).
// CH4 = channels/4; CH4 lanes cooperate per node.

template<int CH4>
__global__ __launch_bounds__(256) void aggregate_split_kernel(
    const float* __restrict__ X, const int* __restrict__ offs,
    const int* __restrict__ srcs, const float* __restrict__ dis,
    unsigned short* __restrict__ Ahi, unsigned short* __restrict__ Alo, int N) {
    constexpr int NPB = 256 / CH4;
    int node = blockIdx.x * NPB + threadIdx.x / CH4;
    if (node >= N) return;
    int lane = threadIdx.x % CH4;
    const float4* Xv = (const float4*)X;
    float dn = dis[node];
    float4 self = Xv[(size_t)node * CH4 + lane];
    float4 acc;
    acc.x = dn * self.x; acc.y = dn * self.y;
    acc.z = dn * self.z; acc.w = dn * self.w;
    float4 acc2 = make_float4(0.f, 0.f, 0.f, 0.f);
    int s = offs[node], e = offs[node + 1];
    int i = s;
    for (; i + 2 <= e; i += 2) {
        int s0 = srcs[i], s1 = srcs[i + 1];
        float d0 = dis[s0], d1 = dis[s1];
        float4 v0 = Xv[(size_t)s0 * CH4 + lane];
        float4 v1 = Xv[(size_t)s1 * CH4 + lane];
        acc.x = fmaf(d0, v0.x, acc.x);   acc.y = fmaf(d0, v0.y, acc.y);
        acc.z = fmaf(d0, v0.z, acc.z);   acc.w = fmaf(d0, v0.w, acc.w);
        acc2.x = fmaf(d1, v1.x, acc2.x); acc2.y = fmaf(d1, v1.y, acc2.y);
        acc2.z = fmaf(d1, v1.z, acc2.z); acc2.w = fmaf(d1, v1.w, acc2.w);
    }
    if (i < e) {
        int s0 = srcs[i];
        float d0 = dis[s0];
        float4 v0 = Xv[(size_t)s0 * CH4 + lane];
        acc.x = fmaf(d0, v0.x, acc.x); acc.y = fmaf(d0, v0.y, acc.y);
        acc.z = fmaf(d0, v0.z, acc.z); acc.w = fmaf(d0, v0.w, acc.w);
    }
    float r[4];
    r[0] = dn * (acc.x + acc2.x); r[1] = dn * (acc.y + acc2.y);
    r[2] = dn * (acc.z + acc2.z); r[3] = dn * (acc.w + acc2.w);
    ushort4 hv, lv;
    unsigned short* hp = (unsigned short*)&hv;
    unsigned short* lp = (unsigned short*)&lv;
    #pragma unroll
    for (int c = 0; c < 4; ++c) {
        unsigned hb = bf16_rne_bits(r[c]);
        float hf = __uint_as_float(hb << 16);
        hp[c] = (unsigned short)hb;
        lp[c] = (unsigned short)bf16_rne_bits(r[c] - hf);
    }
    size_t o = (size_t)node * (CH4 * 4) + lane * 4;
    *(ushort4*)&Ahi[o] = hv;
    *(ushort4*)&Alo[o] = lv;
}

// ---------------- GEMM: H[m,n] = relu( sum_k A[m,k] B[k,n] + bias[n] ) ------
// A as bf16 hi/lo [M][K]; B as transposed bf16 hi/lo [N][K]. 3-pass MFMA.
// 128x128 block tile, BK=32, 4 waves each computing 64x64 (4x4 of 16x16x32).

template<int K>
__global__ __launch_bounds__(256) void gemm_mfma_kernel(
    const unsigned short* __restrict__ Ahi, const unsigned short* __restrict__ Alo,
    const unsigned short* __restrict__ Bhi, const unsigned short* __restrict__ Blo,
    const float* __restrict__ bias, float* __restrict__ H, int M) {
    constexpr int BM = 128, BN = 128, BK = 32, LST = 40;  // LDS stride 40 -> 2-way (free)
    __shared__ unsigned short AsHi[BM * LST], AsLo[BM * LST];
    __shared__ unsigned short BsHi[BN * LST], BsLo[BN * LST];
    int tid = threadIdx.x;
    int m0 = blockIdx.y * BM, n0 = blockIdx.x * BN;
    int wid = tid >> 6, lane = tid & 63;
    int wm = (wid & 1) * 64, wn = (wid >> 1) * 64;
    int l16 = lane & 15, quad = lane >> 4;

    f32x4 acc[4][4] = {};

    for (int k0 = 0; k0 < K; k0 += BK) {
        #pragma unroll
        for (int rep = 0; rep < 2; ++rep) {
            int idx = tid + rep * 256;
            int r = idx >> 2, seg = idx & 3;
            int gr = m0 + r;
            uint4 vh = make_uint4(0, 0, 0, 0), vl = make_uint4(0, 0, 0, 0);
            if (gr < M) {
                vh = *(const uint4*)&Ahi[(size_t)gr * K + k0 + seg * 8];
                vl = *(const uint4*)&Alo[(size_t)gr * K + k0 + seg * 8];
            }
            *(uint4*)&AsHi[r * LST + seg * 8] = vh;
            *(uint4*)&AsLo[r * LST + seg * 8] = vl;
            uint4 wh = *(const uint4*)&Bhi[(size_t)(n0 + r) * K + k0 + seg * 8];
            uint4 wl = *(const uint4*)&Blo[(size_t)(n0 + r) * K + k0 + seg * 8];
            *(uint4*)&BsHi[r * LST + seg * 8] = wh;
            *(uint4*)&BsLo[r * LST + seg * 8] = wl;
        }
        __syncthreads();
        bf16x8 bh[4], bl[4];
        #pragma unroll
        for (int ni = 0; ni < 4; ++ni) {
            int n = wn + ni * 16 + l16;
            bh[ni] = *(const bf16x8*)&BsHi[n * LST + quad * 8];
            bl[ni] = *(const bf16x8*)&BsLo[n * LST + quad * 8];
        }
        #pragma unroll
        for (int mi = 0; mi < 4; ++mi) {
            int m = wm + mi * 16 + l16;
            bf16x8 ah = *(const bf16x8*)&AsHi[m * LST + quad * 8];
            bf16x8 al = *(const bf16x8*)&AsLo[m * LST + quad * 8];
            #pragma unroll
            for (int ni = 0; ni < 4; ++ni) {
                acc[mi][ni] = __builtin_amdgcn_mfma_f32_16x16x32_bf16(ah, bh[ni], acc[mi][ni], 0, 0, 0);
                acc[mi][ni] = __builtin_amdgcn_mfma_f32_16x16x32_bf16(ah, bl[ni], acc[mi][ni], 0, 0, 0);
                acc[mi][ni] = __builtin_amdgcn_mfma_f32_16x16x32_bf16(al, bh[ni], acc[mi][ni], 0, 0, 0);
            }
        }
        __syncthreads();
    }
    #pragma unroll
    for (int mi = 0; mi < 4; ++mi) {
        #pragma unroll
        for (int ni = 0; ni < 4; ++ni) {
            int col = n0 + wn + ni * 16 + l16;
            float bv = bias[col];
            #pragma unroll
            for (int r = 0; r < 4; ++r) {
                int grow = m0 + wm + mi * 16 + quad * 4 + r;
                if (grow < M) {
                    float v = acc[mi][ni][r] + bv;
                    H[(size_t)grow * 256 + col] = fmaxf(v, 0.f);
                }
            }
        }
    }
}

// ---------------- mean pool per graph (batch sorted -> contiguous ranges) ----

__global__ __launch_bounds__(256) void pool_kernel(
    const float* __restrict__ H, const int* __restrict__ goff,
    float* __restrict__ pooled) {
    int g = blockIdx.x;
    int t = threadIdx.x;
    int s = goff[g], e = goff[g + 1];
    float acc = 0.f;
    for (int n = s; n < e; ++n) acc += H[(size_t)n * 256 + t];
    float cnt = (float)(e - s);
    pooled[g * 256 + t] = acc / fmaxf(cnt, 1.f);
}

// ---------------- FFN: relu(pooled@Wf+bf) @ Wo + bo,  one block per graph ----

__global__ __launch_bounds__(256) void ffn_kernel(
    const float* __restrict__ pooled, const float* __restrict__ Wf,
    const float* __restrict__ bf, const float* __restrict__ Wo,
    const float* __restrict__ bo, float* __restrict__ out) {
    __shared__ float p[256];
    __shared__ float red[256];
    int g = blockIdx.x, t = threadIdx.x;
    p[t] = pooled[g * 256 + t];
    __syncthreads();
    float s = bf[t];
    for (int k = 0; k < 256; ++k) s = fmaf(p[k], Wf[k * 256 + t], s);
    float gv = fmaxf(s, 0.f);
    red[t] = gv * Wo[t];
    __syncthreads();
    for (int o = 128; o > 0; o >>= 1) {
        if (t < o) red[t] += red[t + o];
        __syncthreads();
    }
    if (t == 0) out[g] = red[0] + bo[0];
}

// ---------------------------------------------------------------------------

extern "C" void kernel_launch(void* const* d_in, const int* in_sizes, int n_in,
                              void* d_out, int out_size, void* d_ws, size_t ws_size,
                              hipStream_t stream) {
    const float* x   = (const float*)d_in[0];
    const int*   ei  = (const int*)d_in[1];
    const int*   bat = (const int*)d_in[2];
    const float* W1  = (const float*)d_in[3];
    const float* b1  = (const float*)d_in[4];
    const float* W2  = (const float*)d_in[5];
    const float* b2  = (const float*)d_in[6];
    const float* W3  = (const float*)d_in[7];
    const float* b3  = (const float*)d_in[8];
    const float* Wf  = (const float*)d_in[9];
    const float* bf  = (const float*)d_in[10];
    const float* Wo  = (const float*)d_in[11];
    const float* bo  = (const float*)d_in[12];
    float* out = (float*)d_out;

    const int N  = in_sizes[2];        // 50000
    const int E  = in_sizes[1] / 2;    // 800000
    const int IC = in_sizes[0] / N;    // 128
    const int HID = 256;
    const int G  = out_size;           // 256
    const int* row = ei;
    const int* col = ei + E;

    char* w = (char*)d_ws;
    size_t off = 0;
    auto alloc = [&](size_t bytes) -> void* {
        void* p = w + off;
        off += (bytes + 255) & ~(size_t)255;
        return p;
    };
    int*   deg    = (int*)alloc((size_t)N * 4);
    float* dis    = (float*)alloc((size_t)N * 4);
    int*   offs   = (int*)alloc((size_t)(N + 1) * 4);
    int*   srcs   = (int*)alloc((size_t)E * 4);
    int*   gcnt   = (int*)alloc((size_t)G * 4);
    int*   goff   = (int*)alloc((size_t)(G + 1) * 4);
    unsigned short* W1hi = (unsigned short*)alloc((size_t)HID * IC * 2);
    unsigned short* W1lo = (unsigned short*)alloc((size_t)HID * IC * 2);
    unsigned short* W2hi = (unsigned short*)alloc((size_t)HID * HID * 2);
    unsigned short* W2lo = (unsigned short*)alloc((size_t)HID * HID * 2);
    unsigned short* W3hi = (unsigned short*)alloc((size_t)HID * HID * 2);
    unsigned short* W3lo = (unsigned short*)alloc((size_t)HID * HID * 2);
    unsigned short* Ahi  = (unsigned short*)alloc((size_t)N * HID * 2);
    unsigned short* Alo  = (unsigned short*)alloc((size_t)N * HID * 2);
    float* Hbuf   = (float*)alloc((size_t)N * HID * 4);
    float* pooled = (float*)alloc((size_t)G * HID * 4);
    (void)ws_size; (void)n_in;

    hipMemsetAsync(deg,  0, (size_t)N * 4, stream);
    hipMemsetAsync(gcnt, 0, (size_t)G * 4, stream);

    degree_kernel<<<(E + THREADS - 1) / THREADS, THREADS, 0, stream>>>(col, deg, E);
    dis_kernel<<<(N + THREADS - 1) / THREADS, THREADS, 0, stream>>>(deg, dis, N);
    exscan_kernel<<<1, THREADS, 0, stream>>>(deg, offs, N);
    csr_fill_kernel<<<(E + THREADS - 1) / THREADS, THREADS, 0, stream>>>(row, col, offs, deg, srcs, E);
    gcount_kernel<<<(N + THREADS - 1) / THREADS, THREADS, 0, stream>>>(bat, gcnt, N);
    exscan_kernel<<<1, THREADS, 0, stream>>>(gcnt, goff, G);

    wsplit_kernel<<<(IC * HID + THREADS - 1) / THREADS, THREADS, 0, stream>>>(W1, W1hi, W1lo, IC, HID);
    wsplit_kernel<<<(HID * HID + THREADS - 1) / THREADS, THREADS, 0, stream>>>(W2, W2hi, W2lo, HID, HID);
    wsplit_kernel<<<(HID * HID + THREADS - 1) / THREADS, THREADS, 0, stream>>>(W3, W3hi, W3lo, HID, HID);

    dim3 ggrid(HID / 128, (N + 127) / 128);
    // layer 1: aggregate x (128 ch) -> A buffers; GEMM K=128 -> Hbuf
    aggregate_split_kernel<32><<<(N + 7) / 8, 256, 0, stream>>>(x, offs, srcs, dis, Ahi, Alo, N);
    gemm_mfma_kernel<128><<<ggrid, 256, 0, stream>>>(Ahi, Alo, W1hi, W1lo, b1, Hbuf, N);
    // layer 2
    aggregate_split_kernel<64><<<(N + 3) / 4, 256, 0, stream>>>(Hbuf, offs, srcs, dis, Ahi, Alo, N);
    gemm_mfma_kernel<256><<<ggrid, 256, 0, stream>>>(Ahi, Alo, W2hi, W2lo, b2, Hbuf, N);
    // layer 3
    aggregate_split_kernel<64><<<(N + 3) / 4, 256, 0, stream>>>(Hbuf, offs, srcs, dis, Ahi, Alo, N);
    gemm_mfma_kernel<256><<<ggrid, 256, 0, stream>>>(Ahi, Alo, W3hi, W3lo, b3, Hbuf, N);

    pool_kernel<<<G, 256, 0, stream>>>(Hbuf, goff, pooled);
    ffn_kernel<<<G, 256, 0, stream>>>(pooled, Wf, bf, Wo, bo, out);
}